// Round 1
// baseline (73.551 us; speedup 1.0000x reference)
//
#include <hip/hip_runtime.h>
#include <math.h>

#define EPSF 1e-7f

// ---------------------------------------------------------------------------
// Chamfer partial sums.
// grid = 256 blocks: bit7 = direction (pred->targ vs targ->pred),
// bits6..4 = batch (8), bits3..0 = 256-point query chunk (16).
// Each block: stage the full 4096-point database (for its batch) into LDS as
// float4(x,y,z,|p|^2), then each thread computes the NN distance of one query
// point via  min_m (n2[m] - 2<q,p_m>) + |q|^2, and the block writes the sum of
// its 256 sqrt'd min-distances to ws[blockIdx.x].  Deterministic (no atomics).
// ---------------------------------------------------------------------------
__global__ __launch_bounds__(256) void chamfer_partial(
    const float* __restrict__ pred, const float* __restrict__ targ,
    float* __restrict__ ws)
{
    const int NP = 4096;
    const int bid   = blockIdx.x;
    const int dir   = bid >> 7;
    const int b     = (bid >> 4) & 7;
    const int chunk = bid & 15;
    const float* Q = dir ? targ : pred;   // query set
    const float* D = dir ? pred : targ;   // database set

    __shared__ float4 db[4096];           // 64 KB

    const float* Db = D + (size_t)b * NP * 3;
    const int tid = threadIdx.x;
#pragma unroll
    for (int i = 0; i < 16; ++i) {
        int idx = i * 256 + tid;
        float x = Db[idx * 3 + 0];
        float y = Db[idx * 3 + 1];
        float z = Db[idx * 3 + 2];
        db[idx] = make_float4(x, y, z, fmaf(x, x, fmaf(y, y, z * z)));
    }
    __syncthreads();

    const int qi = chunk * 256 + tid;
    const float* Qp = Q + ((size_t)b * NP + qi) * 3;
    const float qx = Qp[0], qy = Qp[1], qz = Qp[2];
    const float n1 = fmaf(qx, qx, fmaf(qy, qy, qz * qz));

    // 4 independent min accumulators to break the v_min_f32 dep chain.
    float m0 = 3.4e38f, m1 = 3.4e38f, m2 = 3.4e38f, m3 = 3.4e38f;
#pragma unroll 4
    for (int m = 0; m < NP; m += 4) {
        float4 a = db[m + 0];
        float4 c = db[m + 1];
        float4 e = db[m + 2];
        float4 f = db[m + 3];
        m0 = fminf(m0, fmaf(-2.f, fmaf(qx, a.x, fmaf(qy, a.y, qz * a.z)), a.w));
        m1 = fminf(m1, fmaf(-2.f, fmaf(qx, c.x, fmaf(qy, c.y, qz * c.z)), c.w));
        m2 = fminf(m2, fmaf(-2.f, fmaf(qx, e.x, fmaf(qy, e.y, qz * e.z)), e.w));
        m3 = fminf(m3, fmaf(-2.f, fmaf(qx, f.x, fmaf(qy, f.y, qz * f.z)), f.w));
    }
    float d2 = fminf(fminf(m0, m1), fminf(m2, m3)) + n1;
    float dist = sqrtf(fmaxf(d2, 1e-12f));

    // block-sum of dist: wave64 butterfly, then cross-wave via LDS (reuse db).
    for (int off = 32; off > 0; off >>= 1)
        dist += __shfl_xor(dist, off);

    __syncthreads();                       // all reads of db done
    float* red = (float*)db;
    if ((tid & 63) == 0) red[tid >> 6] = dist;
    __syncthreads();
    if (tid == 0) ws[bid] = red[0] + red[1] + red[2] + red[3];
}

// ---------------------------------------------------------------------------
// Finalize: sum the 256 chamfer partials, compute BCE (mean over bs*K) and the
// box-constraint term CR, write the scalar result. Single block, deterministic.
// ---------------------------------------------------------------------------
__global__ __launch_bounds__(256) void finalize_kernel(
    const float* __restrict__ ws,
    const float* __restrict__ prob_pred, const float* __restrict__ prob_target,
    const float* __restrict__ mu, const float* __restrict__ lb,
    const float* __restrict__ ub,
    float* __restrict__ out, int nprob, int K)
{
    const int tid = threadIdx.x;

    // BCE partial (un-negated, un-averaged)
    float bce = 0.f;
    const float pmax = 1.0f - EPSF;
    for (int i = tid; i < nprob; i += 256) {
        float p = prob_pred[i];
        p = fminf(fmaxf(p, EPSF), pmax);
        float t = prob_target[i];
        bce += t * logf(p) + (1.0f - t) * log1pf(-p);
    }

    // CR partial
    float cr = 0.f;
    const float invK = 1.0f / (float)K;
    for (int i = tid; i < K; i += 256) {
        float c = fabsf(mu[i]) - 0.5f * (lb[i] + ub[i]) + invK;
        cr += fmaxf(c, 0.f);
    }

    // CD partial: one ws entry per thread (exactly 256 entries)
    float v1 = ws[tid] + cr;   // CD + CR
    float v2 = bce;            // BCE sum (to be negated / averaged)

    for (int off = 32; off > 0; off >>= 1) {
        v1 += __shfl_xor(v1, off);
        v2 += __shfl_xor(v2, off);
    }
    __shared__ float s1[4], s2[4];
    if ((tid & 63) == 0) { s1[tid >> 6] = v1; s2[tid >> 6] = v2; }
    __syncthreads();
    if (tid == 0) {
        float V1 = s1[0] + s1[1] + s1[2] + s1[3];
        float V2 = s2[0] + s2[1] + s2[2] + s2[3];
        out[0] = V1 - V2 / (float)nprob;
    }
}

extern "C" void kernel_launch(void* const* d_in, const int* in_sizes, int n_in,
                              void* d_out, int out_size, void* d_ws, size_t ws_size,
                              hipStream_t stream) {
    const float* prob_pred   = (const float*)d_in[0];
    const float* prob_target = (const float*)d_in[1];
    const float* x_pred      = (const float*)d_in[2];
    const float* x_target    = (const float*)d_in[3];
    const float* mu          = (const float*)d_in[4];
    const float* lb          = (const float*)d_in[5];
    const float* ub          = (const float*)d_in[6];
    float* out = (float*)d_out;
    float* ws  = (float*)d_ws;

    const int K     = in_sizes[4];       // 1000
    const int nprob = in_sizes[0];       // bs*K = 8000

    // 2 directions x 8 batches x 16 chunks = 256 blocks
    chamfer_partial<<<256, 256, 0, stream>>>(x_pred, x_target, ws);
    finalize_kernel<<<1, 256, 0, stream>>>(ws, prob_pred, prob_target,
                                           mu, lb, ub, out, nprob, K);
}

// Round 2
// 54.343 us; speedup vs baseline: 1.3535x; 1.3535x over previous
//
#include <hip/hip_runtime.h>
#include <math.h>

#define EPSF 1e-7f
#define NP    4096     // points per set (N == M)
#define DTILE 256      // db points per LDS tile
#define QPT   8        // queries per thread

// ---------------------------------------------------------------------------
// Stage 1: per-(query, db-tile-group) partial min of (|p|^2 - 2<q,p>).
// grid = (nD, 2, 16): x = db tile-group, y = query chunk, z = dir*8 + batch.
// Each thread holds QPT=8 queries in registers; the 256-point db tile lives in
// LDS pre-scaled as (-2x,-2y,-2z,|p|^2) so each pair is 3 FMA + fused min3.
// Writes per-query partial mins (no |q|^2 yet) to ws[dtg][dir][b][q].
// ---------------------------------------------------------------------------
__global__ __launch_bounds__(256) void chamfer_tile_min(
    const float* __restrict__ pred, const float* __restrict__ targ,
    float* __restrict__ ws, int dtPerBlock)
{
    const int tid = threadIdx.x;
    const int dtg = blockIdx.x;
    const int qc  = blockIdx.y;
    const int dir = blockIdx.z >> 3;
    const int b   = blockIdx.z & 7;

    const float* Q = dir ? targ : pred;
    const float* D = dir ? pred : targ;

    __shared__ float4 tile[DTILE];

    float qx[QPT], qy[QPT], qz[QPT], mn[QPT];
    const int qbase = qc * 2048 + tid;
    const float* Qb = Q + (size_t)b * NP * 3;
#pragma unroll
    for (int j = 0; j < QPT; ++j) {
        const float* qp = Qb + (size_t)(qbase + j * 256) * 3;
        qx[j] = qp[0]; qy[j] = qp[1]; qz[j] = qp[2];
        mn[j] = 3.4e38f;
    }

    const float* Dbase = D + (size_t)b * NP * 3;
    for (int tt = 0; tt < dtPerBlock; ++tt) {
        const int pbase = (dtg * dtPerBlock + tt) * DTILE;
        {
            const float* dp = Dbase + (size_t)(pbase + tid) * 3;
            float x = dp[0], y = dp[1], z = dp[2];
            tile[tid] = make_float4(-2.f * x, -2.f * y, -2.f * z,
                                    fmaf(x, x, fmaf(y, y, z * z)));
        }
        __syncthreads();
#pragma unroll 2
        for (int m = 0; m < DTILE; m += 4) {
            float4 p0 = tile[m + 0], p1 = tile[m + 1];
            float4 p2 = tile[m + 2], p3 = tile[m + 3];
#pragma unroll
            for (int j = 0; j < QPT; ++j) {
                float d0 = fmaf(qx[j], p0.x, fmaf(qy[j], p0.y, fmaf(qz[j], p0.z, p0.w)));
                float d1 = fmaf(qx[j], p1.x, fmaf(qy[j], p1.y, fmaf(qz[j], p1.z, p1.w)));
                mn[j] = fminf(mn[j], fminf(d0, d1));   // -> v_min3_f32
                float d2 = fmaf(qx[j], p2.x, fmaf(qy[j], p2.y, fmaf(qz[j], p2.z, p2.w)));
                float d3 = fmaf(qx[j], p3.x, fmaf(qy[j], p3.y, fmaf(qz[j], p3.z, p3.w)));
                mn[j] = fminf(mn[j], fminf(d2, d3));
            }
        }
        __syncthreads();
    }

    // ws index = dtg*65536 + dir*32768 + b*4096 + qlocal
    float* w = ws + ((((size_t)dtg * 2 + dir) * 8 + b) << 12) + qc * 2048 + tid;
#pragma unroll
    for (int j = 0; j < QPT; ++j) w[j * 256] = mn[j];
}

// ---------------------------------------------------------------------------
// Stage 2: per query, min over db tile-groups, + |q|^2, sqrt, block-sum.
// 64 blocks x 256 threads, 4 queries/thread. Writes ws2[blockIdx.x].
// ---------------------------------------------------------------------------
__global__ __launch_bounds__(256) void chamfer_reduce(
    const float* __restrict__ pred, const float* __restrict__ targ,
    const float* __restrict__ ws, float* __restrict__ ws2, int nD)
{
    const int tid = threadIdx.x;
    const int t = blockIdx.x * 256 + tid;
    float s = 0.f;
#pragma unroll
    for (int k = 0; k < 4; ++k) {
        int idx = t + k * 16384;           // dir*32768 + b*4096 + q
        int dir = idx >> 15;
        int b   = (idx >> 12) & 7;
        int q   = idx & 4095;
        const float* qp = (dir ? targ : pred) + ((size_t)b * NP + q) * 3;
        float x = qp[0], y = qp[1], z = qp[2];
        float n1 = fmaf(x, x, fmaf(y, y, z * z));
        float m = 3.4e38f;
        for (int d = 0; d < nD; ++d) m = fminf(m, ws[(size_t)d * 65536 + idx]);
        s += sqrtf(fmaxf(m + n1, 1e-12f));
    }
    for (int off = 32; off > 0; off >>= 1) s += __shfl_xor(s, off);
    __shared__ float red[4];
    if ((tid & 63) == 0) red[tid >> 6] = s;
    __syncthreads();
    if (tid == 0) ws2[blockIdx.x] = red[0] + red[1] + red[2] + red[3];
}

// ---------------------------------------------------------------------------
// Finalize: sum npart chamfer partials + BCE + CR -> scalar.
// ---------------------------------------------------------------------------
__global__ __launch_bounds__(256) void finalize_kernel(
    const float* __restrict__ parts,
    const float* __restrict__ prob_pred, const float* __restrict__ prob_target,
    const float* __restrict__ mu, const float* __restrict__ lb,
    const float* __restrict__ ub,
    float* __restrict__ out, int nprob, int K, int npart)
{
    const int tid = threadIdx.x;

    float bce = 0.f;
    const float pmax = 1.0f - EPSF;
    for (int i = tid; i < nprob; i += 256) {
        float p = prob_pred[i];
        p = fminf(fmaxf(p, EPSF), pmax);
        float t = prob_target[i];
        bce += t * logf(p) + (1.0f - t) * log1pf(-p);
    }

    float cr = 0.f;
    const float invK = 1.0f / (float)K;
    for (int i = tid; i < K; i += 256) {
        float c = fabsf(mu[i]) - 0.5f * (lb[i] + ub[i]) + invK;
        cr += fmaxf(c, 0.f);
    }

    float v1 = (tid < npart ? parts[tid] : 0.f) + cr;
    float v2 = bce;

    for (int off = 32; off > 0; off >>= 1) {
        v1 += __shfl_xor(v1, off);
        v2 += __shfl_xor(v2, off);
    }
    __shared__ float s1[4], s2[4];
    if ((tid & 63) == 0) { s1[tid >> 6] = v1; s2[tid >> 6] = v2; }
    __syncthreads();
    if (tid == 0) {
        float V1 = s1[0] + s1[1] + s1[2] + s1[3];
        float V2 = s2[0] + s2[1] + s2[2] + s2[3];
        out[0] = V1 - V2 / (float)nprob;
    }
}

// ---------------------------------------------------------------------------
// Fallback (tiny ws): round-0 monolithic chamfer, 256 partial sums.
// ---------------------------------------------------------------------------
__global__ __launch_bounds__(256) void chamfer_partial_mono(
    const float* __restrict__ pred, const float* __restrict__ targ,
    float* __restrict__ ws)
{
    const int bid   = blockIdx.x;
    const int dir   = bid >> 7;
    const int b     = (bid >> 4) & 7;
    const int chunk = bid & 15;
    const float* Q = dir ? targ : pred;
    const float* D = dir ? pred : targ;

    __shared__ float4 db[NP];
    const float* Db = D + (size_t)b * NP * 3;
    const int tid = threadIdx.x;
#pragma unroll
    for (int i = 0; i < 16; ++i) {
        int idx = i * 256 + tid;
        float x = Db[idx * 3 + 0], y = Db[idx * 3 + 1], z = Db[idx * 3 + 2];
        db[idx] = make_float4(-2.f * x, -2.f * y, -2.f * z,
                              fmaf(x, x, fmaf(y, y, z * z)));
    }
    __syncthreads();

    const int qi = chunk * 256 + tid;
    const float* Qp = Q + ((size_t)b * NP + qi) * 3;
    const float qx = Qp[0], qy = Qp[1], qz = Qp[2];
    const float n1 = fmaf(qx, qx, fmaf(qy, qy, qz * qz));

    float m0 = 3.4e38f, m1 = 3.4e38f;
#pragma unroll 4
    for (int m = 0; m < NP; m += 2) {
        float4 a = db[m + 0];
        float4 c = db[m + 1];
        m0 = fminf(m0, fmaf(qx, a.x, fmaf(qy, a.y, fmaf(qz, a.z, a.w))));
        m1 = fminf(m1, fmaf(qx, c.x, fmaf(qy, c.y, fmaf(qz, c.z, c.w))));
    }
    float dist = sqrtf(fmaxf(fminf(m0, m1) + n1, 1e-12f));

    for (int off = 32; off > 0; off >>= 1) dist += __shfl_xor(dist, off);
    __syncthreads();
    float* red = (float*)db;
    if ((tid & 63) == 0) red[tid >> 6] = dist;
    __syncthreads();
    if (tid == 0) ws[bid] = red[0] + red[1] + red[2] + red[3];
}

extern "C" void kernel_launch(void* const* d_in, const int* in_sizes, int n_in,
                              void* d_out, int out_size, void* d_ws, size_t ws_size,
                              hipStream_t stream) {
    const float* prob_pred   = (const float*)d_in[0];
    const float* prob_target = (const float*)d_in[1];
    const float* x_pred      = (const float*)d_in[2];
    const float* x_target    = (const float*)d_in[3];
    const float* mu          = (const float*)d_in[4];
    const float* lb          = (const float*)d_in[5];
    const float* ub          = (const float*)d_in[6];
    float* out = (float*)d_out;
    float* ws  = (float*)d_ws;

    const int K     = in_sizes[4];       // 1000
    const int nprob = in_sizes[0];       // bs*K = 8000

    int nD = 0;
    for (int cand = 16; cand >= 1; cand >>= 1) {
        if (ws_size >= ((size_t)cand * 65536 + 64) * sizeof(float)) { nD = cand; break; }
    }

    if (nD > 0) {
        dim3 grid(nD, 2, 16);
        chamfer_tile_min<<<grid, 256, 0, stream>>>(x_pred, x_target, ws, 16 / nD);
        float* ws2 = ws + (size_t)nD * 65536;
        chamfer_reduce<<<64, 256, 0, stream>>>(x_pred, x_target, ws, ws2, nD);
        finalize_kernel<<<1, 256, 0, stream>>>(ws2, prob_pred, prob_target,
                                               mu, lb, ub, out, nprob, K, 64);
    } else {
        chamfer_partial_mono<<<256, 256, 0, stream>>>(x_pred, x_target, ws);
        finalize_kernel<<<1, 256, 0, stream>>>(ws, prob_pred, prob_target,
                                               mu, lb, ub, out, nprob, K, 256);
    }
}